// Round 8
// baseline (369.432 us; speedup 1.0000x reference)
//
#include <hip/hip_runtime.h>
#include <hip/hip_bf16.h>

typedef unsigned short u16;
typedef short bf16x8 __attribute__((ext_vector_type(8)));   // 8 bf16 = 4 VGPRs
typedef float f32x4 __attribute__((ext_vector_type(4)));

#define SS_PTS 2048

// workspace byte offsets (all 16B-aligned)
#define OFF_IDX   0ULL         // int  [65536*3]
#define OFF_W     786432ULL    // f32  [65536*3]
#define OFF_ST1   1802240ULL   // f32  [512]
#define OFF_ST2   1804288ULL   // f32  [256]
#define OFF_P1    1805312ULL   // f32  [1024][512]
#define OFF_P2    3902464ULL   // f32  [1024][256]
#define OFF_H1    4950016ULL   // bf16 tiled [8][65536][32]
#define OFF_H2    38504448ULL  // bf16 [65536][128]; ALSO G [16384][256] bf16
                               // (G consumed by gemm1 before gemm2 writes h2)

__device__ __forceinline__ u16 f2bf(float x) {
    union { __hip_bfloat16 h; u16 u; } cv;
    cv.h = __float2bfloat16(x);
    return cv.u;
}
__device__ __forceinline__ float bf2f(u16 u) {
    union { unsigned int i; float f; } cv;
    cv.i = ((unsigned int)u) << 16;
    return cv.f;
}
__device__ __forceinline__ float4 pack8(const float* v) {
    union { u16 u[8]; float4 f; } pk;
    #pragma unroll
    for (int j = 0; j < 8; ++j) pk.u[j] = f2bf(v[j]);
    return pk.f;
}
__device__ __forceinline__ float4 pack8v(float4 a, float4 b) {
    float v[8] = {a.x, a.y, a.z, a.w, b.x, b.y, b.z, b.w};
    return pack8(v);
}

// ---------------------------------------------------------------- GEMM0
// G[16384][256] = points2[16384][256] @ W1b^T  (W1b = W1 cols 64..319, fp32,
// converted to bf16 in staging — identical rounding to the old prep path)
__global__ __launch_bounds__(256) void gemm0_kernel(
    const float* __restrict__ points2, const float* __restrict__ W1,
    u16* __restrict__ G) {
    __shared__ __align__(16) u16 Bs[8192];   // 256 rows x 32 k, XOR-swizzled

    int t = threadIdx.x, bx = blockIdx.x;
    int R0 = bx * 64;
    int w = t >> 6, l = t & 63, l15 = l & 15, q = l >> 4;
    int wr = (w >> 1) * 32, wc = (w & 1) * 128;
    int bm = t >> 1, bh = t & 1;
    int sb0 = (bm >> 1) & 3, sb1 = ((bm + 128) >> 1) & 3;
    const float* ws0 = W1 + (size_t)bm * 320 + 64 + bh * 16;
    const float* ws1 = W1 + (size_t)(bm + 128) * 320 + 64 + bh * 16;

    float4 pa0 = ((const float4*)ws0)[0], pa1 = ((const float4*)ws0)[1];
    float4 pa2 = ((const float4*)ws0)[2], pa3 = ((const float4*)ws0)[3];
    float4 pc0 = ((const float4*)ws1)[0], pc1 = ((const float4*)ws1)[1];
    float4 pc2 = ((const float4*)ws1)[2], pc3 = ((const float4*)ws1)[3];

    f32x4 acc[2][8];
    #pragma unroll
    for (int i = 0; i < 2; ++i)
        #pragma unroll
        for (int j = 0; j < 8; ++j) acc[i][j] = (f32x4){0.f, 0.f, 0.f, 0.f};

    #pragma unroll
    for (int kb = 0; kb < 8; ++kb) {
        *(float4*)&Bs[bm * 32 + (((bh * 2 + 0) ^ sb0) << 3)] = pack8v(pa0, pa1);
        *(float4*)&Bs[bm * 32 + (((bh * 2 + 1) ^ sb0) << 3)] = pack8v(pa2, pa3);
        *(float4*)&Bs[(bm + 128) * 32 + (((bh * 2 + 0) ^ sb1) << 3)] = pack8v(pc0, pc1);
        *(float4*)&Bs[(bm + 128) * 32 + (((bh * 2 + 1) ^ sb1) << 3)] = pack8v(pc2, pc3);
        __syncthreads();
        if (kb < 7) {
            const float* n0 = ws0 + (kb + 1) * 32;
            const float* n1 = ws1 + (kb + 1) * 32;
            pa0 = ((const float4*)n0)[0]; pa1 = ((const float4*)n0)[1];
            pa2 = ((const float4*)n0)[2]; pa3 = ((const float4*)n0)[3];
            pc0 = ((const float4*)n1)[0]; pc1 = ((const float4*)n1)[1];
            pc2 = ((const float4*)n1)[2]; pc3 = ((const float4*)n1)[3];
        }
        union uf { float4 f; bf16x8 v; };
        uf af[2], bf8[8];
        #pragma unroll
        for (int fi = 0; fi < 2; ++fi) {
            int ml = wr + fi * 16 + l15;
            const float* s = points2 + (size_t)(R0 + ml) * 256 + kb * 32 + q * 8;
            float4 x0 = ((const float4*)s)[0], x1 = ((const float4*)s)[1];
            af[fi].f = pack8v(x0, x1);
        }
        #pragma unroll
        for (int fj = 0; fj < 8; ++fj) {
            int nl = wc + fj * 16 + l15;
            bf8[fj].f = *(const float4*)&Bs[nl * 32 + ((q ^ ((nl >> 1) & 3)) << 3)];
        }
        #pragma unroll
        for (int fi = 0; fi < 2; ++fi)
            #pragma unroll
            for (int fj = 0; fj < 8; ++fj)
                acc[fi][fj] = __builtin_amdgcn_mfma_f32_16x16x32_bf16(
                    bf8[fj].v, af[fi].v, acc[fi][fj], 0, 0, 0);
        __syncthreads();
    }

    #pragma unroll
    for (int fi = 0; fi < 2; ++fi) {
        int rg = R0 + wr + fi * 16 + l15;
        #pragma unroll
        for (int fj = 0; fj < 8; ++fj) {
            int cl = wc + fj * 16 + q * 4;
            union { u16 u[4]; float2 f; } pk;
            #pragma unroll
            for (int i = 0; i < 4; ++i) pk.u[i] = f2bf(acc[fi][fj][i]);
            *(float2*)&G[(size_t)rg * 256 + cl] = pk.f;
        }
    }
}

// ---------------------------------------------------------------- 3-NN v8
// 128 queries/block (2 per lane), 4 partitions; branchless top-3 insert
// (strict <, bit-identical selection & tie-break vs the branchy version).
// One LDS point-read feeds two evals -> LDS pipe time halved.
__global__ __launch_bounds__(256) void knn_kernel(
    const float* __restrict__ xyz1, const float* __restrict__ xyz2,
    int* __restrict__ idxb, float* __restrict__ wb) {
    __shared__ float4 pts[2051];          // 4 regions of 513 (bank stagger)
    __shared__ float cd[128][13];
    __shared__ int   ci[128][13];
    int t = threadIdx.x;
    int bq = blockIdx.x;                  // 0..511
    int b = bq >> 6;                      // 64 blocks per batch
    const float* x2b = xyz2 + (size_t)b * SS_PTS * 3;
    for (int j = t; j < SS_PTS; j += 256) {
        float x = x2b[j * 3 + 0], y = x2b[j * 3 + 1], z = x2b[j * 3 + 2];
        pts[(j >> 9) * 513 + (j & 511)] = make_float4(x, y, z, x * x + y * y + z * z);
    }
    int lq = t >> 2, p = t & 3;
    int ga = bq * 128 + lq, gb = ga + 64;
    float qxa = xyz1[(size_t)ga * 3 + 0];
    float qya = xyz1[(size_t)ga * 3 + 1];
    float qza = xyz1[(size_t)ga * 3 + 2];
    float qxb = xyz1[(size_t)gb * 3 + 0];
    float qyb = xyz1[(size_t)gb * 3 + 1];
    float qzb = xyz1[(size_t)gb * 3 + 2];
    __syncthreads();

    float m2xa = -2.0f * qxa, m2ya = -2.0f * qya, m2za = -2.0f * qza;
    float m2xb = -2.0f * qxb, m2yb = -2.0f * qyb, m2zb = -2.0f * qzb;
    float d0a = 3.4e38f, d1a = 3.4e38f, d2a = 3.4e38f;
    float d0b = 3.4e38f, d1b = 3.4e38f, d2b = 3.4e38f;
    int j0a = 0, j1a = 0, j2a = 0, j0b = 0, j1b = 0, j2b = 0;
    int base = p * 513, sbase = p * 512;
    #pragma unroll 4
    for (int s = 0; s < 512; ++s) {
        float4 pt = pts[base + s];
        int idx = sbase + s;
        float sca = fmaf(m2xa, pt.x, fmaf(m2ya, pt.y, fmaf(m2za, pt.z, pt.w)));
        float scb = fmaf(m2xb, pt.x, fmaf(m2yb, pt.y, fmaf(m2zb, pt.z, pt.w)));
        bool a0 = sca < d0a, a1 = sca < d1a, a2 = sca < d2a;
        d2a = a1 ? d1a : (a2 ? sca : d2a); j2a = a1 ? j1a : (a2 ? idx : j2a);
        d1a = a0 ? d0a : (a1 ? sca : d1a); j1a = a0 ? j0a : (a1 ? idx : j1a);
        d0a = a0 ? sca : d0a;              j0a = a0 ? idx : j0a;
        bool b0 = scb < d0b, b1 = scb < d1b, b2 = scb < d2b;
        d2b = b1 ? d1b : (b2 ? scb : d2b); j2b = b1 ? j1b : (b2 ? idx : j2b);
        d1b = b0 ? d0b : (b1 ? scb : d1b); j1b = b0 ? j0b : (b1 ? idx : j1b);
        d0b = b0 ? scb : d0b;              j0b = b0 ? idx : j0b;
    }
    int c = p * 3;
    cd[lq][c + 0] = d0a; cd[lq][c + 1] = d1a; cd[lq][c + 2] = d2a;
    ci[lq][c + 0] = j0a; ci[lq][c + 1] = j1a; ci[lq][c + 2] = j2a;
    cd[lq + 64][c + 0] = d0b; cd[lq + 64][c + 1] = d1b; cd[lq + 64][c + 2] = d2b;
    ci[lq + 64][c + 0] = j0b; ci[lq + 64][c + 1] = j1b; ci[lq + 64][c + 2] = j2b;
    __syncthreads();

    if (t < 128) {
        float e0 = 3.4e38f, e1 = 3.4e38f, e2 = 3.4e38f;
        int k0 = 0, k1 = 0, k2 = 0;
        #pragma unroll
        for (int m = 0; m < 12; ++m) {
            float sc = cd[t][m];
            int sj = ci[t][m];
            bool b0 = sc < e0, b1 = sc < e1, b2 = sc < e2;
            e2 = b1 ? e1 : (b2 ? sc : e2); k2 = b1 ? k1 : (b2 ? sj : k2);
            e1 = b0 ? e0 : (b1 ? sc : e1); k1 = b0 ? k0 : (b1 ? sj : k1);
            e0 = b0 ? sc : e0;             k0 = b0 ? sj : k0;
        }
        int g = bq * 128 + t;
        float qx = xyz1[(size_t)g * 3 + 0];
        float qy = xyz1[(size_t)g * 3 + 1];
        float qz = xyz1[(size_t)g * 3 + 2];
        float qq = qx * qx + qy * qy + qz * qz;
        float dd0 = fmaxf(e0 + qq, 1e-10f);
        float dd1 = fmaxf(e1 + qq, 1e-10f);
        float dd2 = fmaxf(e2 + qq, 1e-10f);
        float w0 = 1.0f / dd0, w1 = 1.0f / dd1, w2 = 1.0f / dd2;
        float inv = 1.0f / (w0 + w1 + w2);
        idxb[(size_t)g * 3 + 0] = k0;
        idxb[(size_t)g * 3 + 1] = k1;
        idxb[(size_t)g * 3 + 2] = k2;
        wb[(size_t)g * 3 + 0] = w0 * inv;
        wb[(size_t)g * 3 + 1] = w1 * inv;
        wb[(size_t)g * 3 + 2] = w2 * inv;
    }
}

// ---------------------------------------------------------------- GEMM1 v8
// h1 = points1 @ W1a^T (K=64 MFMA) + Sum_k w_k * G[idx_k].
// W1a staged from fp32 directly (bf16 convert in staging). Stats: shfl-reduce
// into per-wave-pair LDS slices (no atomics).
__global__ __launch_bounds__(256, 3) void gemm1_kernel(
    const float* __restrict__ points1, const u16* __restrict__ G,
    const int* __restrict__ idxb, const float* __restrict__ wb,
    const float* __restrict__ W1, u16* __restrict__ h1, float* __restrict__ part1) {
    __shared__ __align__(16) u16 Si[64 * 258];     // interp bf16, stride 258
    __shared__ __align__(16) u16 Bs[8192];         // W1a tile 256x32, swizzled
    __shared__ float bsum[2][256], bsq[2][256];    // per-wave-pair slices

    int t = threadIdx.x, bx = blockIdx.x;
    int batch = bx & 7;
    int R0 = batch * 8192 + (bx >> 3) * 64;
    const u16* Gb = G + (size_t)batch * SS_PTS * 256;

    int w = t >> 6, l = t & 63, l15 = l & 15, q = l >> 4;
    int wr = (w >> 1) * 32, wc = (w & 1) * 128;

    // ---- phase 1: gather-sum from G into Si; one wave per query row
    {
        #pragma unroll 4
        for (int e = 0; e < 16; ++e) {
            int qi = w * 16 + e;
            size_t gq = (size_t)(R0 + qi) * 3;
            int i0 = idxb[gq + 0], i1 = idxb[gq + 1], i2 = idxb[gq + 2];
            float w0 = wb[gq + 0], w1 = wb[gq + 1], w2 = wb[gq + 2];
            union { float2 f; u16 u[4]; } g0, g1, g2;
            g0.f = *(const float2*)(Gb + (size_t)i0 * 256 + l * 4);
            g1.f = *(const float2*)(Gb + (size_t)i1 * 256 + l * 4);
            g2.f = *(const float2*)(Gb + (size_t)i2 * 256 + l * 4);
            union { u16 u[4]; float2 f; } pk;
            #pragma unroll
            for (int i = 0; i < 4; ++i) {
                float v = fmaf(w0, bf2f(g0.u[i]),
                          fmaf(w1, bf2f(g1.u[i]), w2 * bf2f(g2.u[i])));
                pk.u[i] = f2bf(v);
            }
            *(float2*)&Si[qi * 258 + l * 4] = pk.f;
        }
    }

    // ---- B staging regs (W1a rows, k 0..63, fp32)
    int bm = t >> 1, bh = t & 1;
    int sb0 = (bm >> 1) & 3, sb1 = ((bm + 128) >> 1) & 3;
    const float* ws0 = W1 + (size_t)bm * 320 + bh * 16;
    const float* ws1 = W1 + (size_t)(bm + 128) * 320 + bh * 16;
    float4 pa0 = ((const float4*)ws0)[0], pa1 = ((const float4*)ws0)[1];
    float4 pa2 = ((const float4*)ws0)[2], pa3 = ((const float4*)ws0)[3];
    float4 pc0 = ((const float4*)ws1)[0], pc1 = ((const float4*)ws1)[1];
    float4 pc2 = ((const float4*)ws1)[2], pc3 = ((const float4*)ws1)[3];

    f32x4 acc[2][8];
    #pragma unroll
    for (int i = 0; i < 2; ++i)
        #pragma unroll
        for (int j = 0; j < 8; ++j) acc[i][j] = (f32x4){0.f, 0.f, 0.f, 0.f};

    // ---- phase 2: K-loop (2 x K=32) on points1 @ W1a^T
    #pragma unroll
    for (int kb = 0; kb < 2; ++kb) {
        *(float4*)&Bs[bm * 32 + (((bh * 2 + 0) ^ sb0) << 3)] = pack8v(pa0, pa1);
        *(float4*)&Bs[bm * 32 + (((bh * 2 + 1) ^ sb0) << 3)] = pack8v(pa2, pa3);
        *(float4*)&Bs[(bm + 128) * 32 + (((bh * 2 + 0) ^ sb1) << 3)] = pack8v(pc0, pc1);
        *(float4*)&Bs[(bm + 128) * 32 + (((bh * 2 + 1) ^ sb1) << 3)] = pack8v(pc2, pc3);
        __syncthreads();
        if (kb == 0) {
            pa0 = ((const float4*)(ws0 + 32))[0]; pa1 = ((const float4*)(ws0 + 32))[1];
            pa2 = ((const float4*)(ws0 + 32))[2]; pa3 = ((const float4*)(ws0 + 32))[3];
            pc0 = ((const float4*)(ws1 + 32))[0]; pc1 = ((const float4*)(ws1 + 32))[1];
            pc2 = ((const float4*)(ws1 + 32))[2]; pc3 = ((const float4*)(ws1 + 32))[3];
        }
        union uf { float4 f; bf16x8 v; };
        uf af[2], bf8[8];
        #pragma unroll
        for (int fi = 0; fi < 2; ++fi) {
            int ml = wr + fi * 16 + l15;
            const float* s = points1 + (size_t)(R0 + ml) * 64 + kb * 32 + q * 8;
            float4 x0 = ((const float4*)s)[0], x1 = ((const float4*)s)[1];
            af[fi].f = pack8v(x0, x1);
        }
        #pragma unroll
        for (int fj = 0; fj < 8; ++fj) {
            int nl = wc + fj * 16 + l15;
            bf8[fj].f = *(const float4*)&Bs[nl * 32 + ((q ^ ((nl >> 1) & 3)) << 3)];
        }
        #pragma unroll
        for (int fi = 0; fi < 2; ++fi)
            #pragma unroll
            for (int fj = 0; fj < 8; ++fj)
                acc[fi][fj] = __builtin_amdgcn_mfma_f32_16x16x32_bf16(
                    bf8[fj].v, af[fi].v, acc[fi][fj], 0, 0, 0);
        __syncthreads();
    }

    // ---- epilogue: add interp (Si), store h1 K-tiled, stats via shfl (no atomics)
    #pragma unroll
    for (int fj = 0; fj < 8; ++fj) {
        int c0 = wc + fj * 16 + q * 4;
        float s[4], sq[4];
        #pragma unroll
        for (int i = 0; i < 4; ++i) { s[i] = 0.0f; sq[i] = 0.0f; }
        #pragma unroll
        for (int fi = 0; fi < 2; ++fi) {
            int rl = wr + fi * 16 + l15;
            int rg = R0 + rl;
            union { float2 f; u16 u[4]; } si;
            si.f = *(const float2*)&Si[rl * 258 + c0];
            union { u16 u[4]; float2 f; } pk;
            #pragma unroll
            for (int i = 0; i < 4; ++i) {
                float v = acc[fi][fj][i] + bf2f(si.u[i]);
                pk.u[i] = f2bf(v);
                s[i] += v; sq[i] += v * v;
            }
            *(float2*)&h1[((size_t)(c0 >> 5) * 65536 + rg) * 32 + (c0 & 31)] = pk.f;
        }
        #pragma unroll
        for (int i = 0; i < 4; ++i) {
            #pragma unroll
            for (int d = 1; d < 16; d <<= 1) {
                s[i]  += __shfl_xor(s[i], d, 16);
                sq[i] += __shfl_xor(sq[i], d, 16);
            }
        }
        if (l15 == 0) {
            int half = w >> 1;
            #pragma unroll
            for (int i = 0; i < 4; ++i) {
                bsum[half][c0 + i] = s[i];
                bsq[half][c0 + i]  = sq[i];
            }
        }
    }
    __syncthreads();
    part1[(size_t)bx * 512 + t * 2 + 0] = bsum[0][t] + bsum[1][t];
    part1[(size_t)bx * 512 + t * 2 + 1] = bsq[0][t] + bsq[1][t];
}

// ---------------------------------------------------------------- stats reduce
__global__ __launch_bounds__(256) void reduce_kernel(
    const float* __restrict__ part, int nblk, int C, float invM,
    const float* __restrict__ gam, const float* __restrict__ bet,
    float* __restrict__ st) {
    __shared__ float red[256];
    int t = threadIdx.x;
    int slot = t & 31, ig = t >> 5;
    int cb = blockIdx.x * 16;
    float p = 0.0f;
    for (int i = ig; i < nblk; i += 8)
        p += part[(size_t)i * (2 * C) + cb * 2 + slot];
    red[t] = p;
    __syncthreads();
    if (t < 32) {
        float tot = red[t];
        #pragma unroll
        for (int k = 1; k < 8; ++k) tot += red[k * 32 + t];
        red[t] = tot;
    }
    __syncthreads();
    if (t < 16) {
        int c = cb + t;
        float sum = red[2 * t], sq = red[2 * t + 1];
        float mean = sum * invM;
        float var  = sq * invM - mean * mean;
        float rs   = rsqrtf(var + 1e-5f);
        float scv  = gam[c] * rs;
        st[c]     = scv;
        st[C + c] = bet[c] - mean * scv;
    }
}

// ---------------------------------------------------------------- GEMM2 v8
// 64x128 tile, grid 1024, LDS dbuf + reg prefetch. W2 staged from fp32.
// Stats: shfl + per-wave LDS slices (no atomics).
__global__ __launch_bounds__(256, 4) void gemm2_kernel(
    const u16* __restrict__ h1, const float* __restrict__ W2,
    const float* __restrict__ st1,
    u16* __restrict__ h2, float* __restrict__ part2) {
    __shared__ __align__(16) u16 As[2][64 * 32];
    __shared__ __align__(16) u16 Bs[2][128 * 32];
    __shared__ float sc1[256], sh1[256];
    __shared__ float bsum2[4][128], bsq2[4][128];

    int t = threadIdx.x;
    int bx = blockIdx.x;
    int R0 = bx * 64;
    sc1[t] = st1[t];
    sh1[t] = st1[256 + t];

    int w = t >> 6, l = t & 63, l15 = l & 15, q = l >> 4;
    int wr = w * 16;
    int arow = t >> 2, ac8 = (t & 3) << 3, sa = (arow >> 1) & 3;
    int bm = t >> 1, bh = t & 1, sb = (bm >> 1) & 3;

    union lda_t { float4 f; u16 u[8]; };
    lda_t pa; float4 pb0, pb1, pb2, pb3;
    const float* bsrc = W2 + (size_t)bm * 256 + bh * 16;

    pa.f = *(const float4*)(h1 + ((size_t)0 * 65536 + R0 + arow) * 32 + ac8);
    pb0 = ((const float4*)bsrc)[0];
    pb1 = ((const float4*)bsrc)[1];
    pb2 = ((const float4*)bsrc)[2];
    pb3 = ((const float4*)bsrc)[3];

    f32x4 acc[8];
    #pragma unroll
    for (int j = 0; j < 8; ++j) acc[j] = (f32x4){0.f, 0.f, 0.f, 0.f};

    __syncthreads();   // sc1/sh1 visible

    {
        float o[8];
        #pragma unroll
        for (int j = 0; j < 8; ++j)
            o[j] = fmaxf(fmaf(bf2f(pa.u[j]), sc1[ac8 + j], sh1[ac8 + j]), 0.0f);
        *(float4*)&As[0][arow * 32 + (((ac8 >> 3) ^ sa) << 3)] = pack8(o);
        *(float4*)&Bs[0][bm * 32 + (((bh * 2 + 0) ^ sb) << 3)] = pack8v(pb0, pb1);
        *(float4*)&Bs[0][bm * 32 + (((bh * 2 + 1) ^ sb) << 3)] = pack8v(pb2, pb3);
    }
    __syncthreads();

    #pragma unroll
    for (int kb = 0; kb < 8; ++kb) {
        if (kb < 7) {
            pa.f = *(const float4*)(h1 + ((size_t)(kb + 1) * 65536 + R0 + arow) * 32 + ac8);
            const float* nb = bsrc + (kb + 1) * 32;
            pb0 = ((const float4*)nb)[0];
            pb1 = ((const float4*)nb)[1];
            pb2 = ((const float4*)nb)[2];
            pb3 = ((const float4*)nb)[3];
        }
        int buf = kb & 1;
        union uf { float4 f; bf16x8 v; };
        uf af, bf8[8];
        {
            int ml = wr + l15;
            af.f = *(const float4*)&As[buf][ml * 32 + ((q ^ ((ml >> 1) & 3)) << 3)];
        }
        #pragma unroll
        for (int fj = 0; fj < 8; ++fj) {
            int nl = fj * 16 + l15;
            bf8[fj].f = *(const float4*)&Bs[buf][nl * 32 + ((q ^ ((nl >> 1) & 3)) << 3)];
        }
        #pragma unroll
        for (int fj = 0; fj < 8; ++fj)
            acc[fj] = __builtin_amdgcn_mfma_f32_16x16x32_bf16(
                bf8[fj].v, af.v, acc[fj], 0, 0, 0);
        if (kb < 7) {
            int ch0 = (kb + 1) * 32 + ac8;
            float o[8];
            #pragma unroll
            for (int j = 0; j < 8; ++j)
                o[j] = fmaxf(fmaf(bf2f(pa.u[j]), sc1[ch0 + j], sh1[ch0 + j]), 0.0f);
            *(float4*)&As[buf ^ 1][arow * 32 + (((ac8 >> 3) ^ sa) << 3)] = pack8(o);
            *(float4*)&Bs[buf ^ 1][bm * 32 + (((bh * 2 + 0) ^ sb) << 3)] = pack8v(pb0, pb1);
            *(float4*)&Bs[buf ^ 1][bm * 32 + (((bh * 2 + 1) ^ sb) << 3)] = pack8v(pb2, pb3);
        }
        __syncthreads();
    }

    // ---- epilogue: h2 store + stats via shfl into per-wave slices (no atomics)
    int rg = R0 + wr + l15;
    #pragma unroll
    for (int fj = 0; fj < 8; ++fj) {
        int cl = fj * 16 + q * 4;
        union { u16 u[4]; float2 f; } pk;
        float s[4], sq[4];
        #pragma unroll
        for (int i = 0; i < 4; ++i) {
            float v = acc[fj][i];
            pk.u[i] = f2bf(v);
            s[i] = v; sq[i] = v * v;
        }
        *(float2*)&h2[(size_t)rg * 128 + cl] = pk.f;
        #pragma unroll
        for (int i = 0; i < 4; ++i) {
            #pragma unroll
            for (int d = 1; d < 16; d <<= 1) {
                s[i]  += __shfl_xor(s[i], d, 16);
                sq[i] += __shfl_xor(sq[i], d, 16);
            }
        }
        if (l15 == 0) {
            #pragma unroll
            for (int i = 0; i < 4; ++i) {
                bsum2[w][cl + i] = s[i];
                bsq2[w][cl + i]  = sq[i];
            }
        }
    }
    __syncthreads();
    if (t < 128) {
        part2[(size_t)bx * 256 + t * 2 + 0] =
            bsum2[0][t] + bsum2[1][t] + bsum2[2][t] + bsum2[3][t];
        part2[(size_t)bx * 256 + t * 2 + 1] =
            bsq2[0][t] + bsq2[1][t] + bsq2[2][t] + bsq2[3][t];
    }
}

// ---------------------------------------------------------------- final BN2 + relu
__global__ __launch_bounds__(256) void final_kernel(
    const u16* __restrict__ h2, const float* __restrict__ st2,
    float* __restrict__ out) {
    __shared__ float lst[256];
    int t = threadIdx.x;
    lst[t] = st2[t];
    __syncthreads();
    size_t e0 = ((size_t)blockIdx.x * 256 + t) * 8;
    int c0 = (int)(e0 & 127);
    union { float4 f; u16 u[8]; } ld;
    ld.f = *(const float4*)(h2 + e0);
    float o[8];
    #pragma unroll
    for (int j = 0; j < 8; ++j) {
        int c = c0 + j;
        float v = fmaf(bf2f(ld.u[j]), lst[c], lst[128 + c]);
        o[j] = fmaxf(v, 0.0f);
    }
    float4* op = (float4*)(out + e0);
    float4 r0; r0.x = o[0]; r0.y = o[1]; r0.z = o[2]; r0.w = o[3];
    float4 r1; r1.x = o[4]; r1.y = o[5]; r1.z = o[6]; r1.w = o[7];
    op[0] = r0;
    op[1] = r1;
}

// ----------------------------------------------------------------
extern "C" void kernel_launch(void* const* d_in, const int* in_sizes, int n_in,
                              void* d_out, int out_size, void* d_ws, size_t ws_size,
                              hipStream_t stream) {
    (void)in_sizes; (void)n_in; (void)out_size; (void)ws_size;
    const float* xyz1    = (const float*)d_in[0];
    const float* xyz2    = (const float*)d_in[1];
    const float* points1 = (const float*)d_in[2];
    const float* points2 = (const float*)d_in[3];
    const float* W1      = (const float*)d_in[4];
    const float* g1      = (const float*)d_in[5];
    const float* b1      = (const float*)d_in[6];
    const float* W2      = (const float*)d_in[7];
    const float* g2      = (const float*)d_in[8];
    const float* b2      = (const float*)d_in[9];

    char* ws = (char*)d_ws;
    int*   idxb = (int*)(ws + OFF_IDX);
    float* wb   = (float*)(ws + OFF_W);
    float* st1  = (float*)(ws + OFF_ST1);
    float* st2  = (float*)(ws + OFF_ST2);
    float* p1   = (float*)(ws + OFF_P1);
    float* p2   = (float*)(ws + OFF_P2);
    u16*   h1   = (u16*)(ws + OFF_H1);
    u16*   h2   = (u16*)(ws + OFF_H2);
    u16*   G    = (u16*)(ws + OFF_H2);   // reuse: consumed before h2 is written
    float* outp = (float*)d_out;

    gemm0_kernel<<<256, 256, 0, stream>>>(points2, W1, G);
    knn_kernel<<<512, 256, 0, stream>>>(xyz1, xyz2, idxb, wb);
    gemm1_kernel<<<1024, 256, 0, stream>>>(points1, G, idxb, wb, W1, h1, p1);
    reduce_kernel<<<16, 256, 0, stream>>>(p1, 1024, 256, 1.0f / 65536.0f, g1, b1, st1);
    gemm2_kernel<<<1024, 256, 0, stream>>>(h1, W2, st1, h2, p2);
    reduce_kernel<<<8, 256, 0, stream>>>(p2, 1024, 128, 1.0f / 65536.0f, g2, b2, st2);
    final_kernel<<<4096, 256, 0, stream>>>(h2, st2, outp);
}

// Round 9
// 324.837 us; speedup vs baseline: 1.1373x; 1.1373x over previous
//
#include <hip/hip_runtime.h>
#include <hip/hip_bf16.h>

typedef unsigned short u16;
typedef short bf16x8 __attribute__((ext_vector_type(8)));   // 8 bf16 = 4 VGPRs
typedef float f32x4 __attribute__((ext_vector_type(4)));

#define SS_PTS 2048

// workspace byte offsets (all 16B-aligned)
#define OFF_IDX   0ULL         // int  [65536*3]
#define OFF_W     786432ULL    // f32  [65536*3]
#define OFF_WT1B  1572864ULL   // bf16 [256][320]
#define OFF_WT2B  1736704ULL   // bf16 [128][256]
#define OFF_ST1   1802240ULL   // f32  [512]
#define OFF_ST2   1804288ULL   // f32  [256]
#define OFF_P1    1805312ULL   // f32  [1024][512]
#define OFF_P2    3902464ULL   // f32  [1024][256]
#define OFF_H1    4950016ULL   // bf16 tiled [8][65536][32]
#define OFF_H2    38504448ULL  // bf16 [65536][128]; ALSO G [16384][256] bf16
                               // (G consumed by gemm1 before gemm2 writes h2)

__device__ __forceinline__ u16 f2bf(float x) {
    union { __hip_bfloat16 h; u16 u; } cv;
    cv.h = __float2bfloat16(x);
    return cv.u;
}
__device__ __forceinline__ float bf2f(u16 u) {
    union { unsigned int i; float f; } cv;
    cv.i = ((unsigned int)u) << 16;
    return cv.f;
}
__device__ __forceinline__ float4 pack8(const float* v) {
    union { u16 u[8]; float4 f; } pk;
    #pragma unroll
    for (int j = 0; j < 8; ++j) pk.u[j] = f2bf(v[j]);
    return pk.f;
}

// ---------------------------------------------------------------- prep: W -> bf16
__global__ __launch_bounds__(256) void prep_kernel(
    const float* __restrict__ W1, const float* __restrict__ W2,
    u16* __restrict__ wt1b, u16* __restrict__ wt2b) {
    int i = blockIdx.x * 256 + threadIdx.x;
    if (i < 81920) wt1b[i] = f2bf(W1[i]);
    if (i < 32768) wt2b[i] = f2bf(W2[i]);
}

// ---------------------------------------------------------------- GEMM0
// G[16384][256] = points2[16384][256] @ W1b^T  (W1b = wt1b cols 64..319)
__global__ __launch_bounds__(256) void gemm0_kernel(
    const float* __restrict__ points2, const u16* __restrict__ wt1b,
    u16* __restrict__ G) {
    __shared__ __align__(16) u16 Bs[8192];   // 256 rows x 32 k, XOR-swizzled

    int t = threadIdx.x, bx = blockIdx.x;
    int R0 = bx * 64;
    int w = t >> 6, l = t & 63, l15 = l & 15, q = l >> 4;
    int wr = (w >> 1) * 32, wc = (w & 1) * 128;
    int bm = t >> 1, bh = t & 1;
    int sb0 = (bm >> 1) & 3, sb1 = ((bm + 128) >> 1) & 3;
    const u16* wsrc0 = wt1b + (size_t)bm * 320 + 64 + bh * 16;
    const u16* wsrc1 = wt1b + (size_t)(bm + 128) * 320 + 64 + bh * 16;

    float4 pb0 = ((const float4*)wsrc0)[0], pb1 = ((const float4*)wsrc0)[1];
    float4 pb2 = ((const float4*)wsrc1)[0], pb3 = ((const float4*)wsrc1)[1];

    f32x4 acc[2][8];
    #pragma unroll
    for (int i = 0; i < 2; ++i)
        #pragma unroll
        for (int j = 0; j < 8; ++j) acc[i][j] = (f32x4){0.f, 0.f, 0.f, 0.f};

    #pragma unroll
    for (int kb = 0; kb < 8; ++kb) {
        *(float4*)&Bs[bm * 32 + (((bh * 2 + 0) ^ sb0) << 3)] = pb0;
        *(float4*)&Bs[bm * 32 + (((bh * 2 + 1) ^ sb0) << 3)] = pb1;
        *(float4*)&Bs[(bm + 128) * 32 + (((bh * 2 + 0) ^ sb1) << 3)] = pb2;
        *(float4*)&Bs[(bm + 128) * 32 + (((bh * 2 + 1) ^ sb1) << 3)] = pb3;
        __syncthreads();
        if (kb < 7) {
            pb0 = ((const float4*)(wsrc0 + (kb + 1) * 32))[0];
            pb1 = ((const float4*)(wsrc0 + (kb + 1) * 32))[1];
            pb2 = ((const float4*)(wsrc1 + (kb + 1) * 32))[0];
            pb3 = ((const float4*)(wsrc1 + (kb + 1) * 32))[1];
        }
        union uf { float4 f; bf16x8 v; };
        uf af[2], bf8[8];
        #pragma unroll
        for (int fi = 0; fi < 2; ++fi) {
            int ml = wr + fi * 16 + l15;
            const float* s = points2 + (size_t)(R0 + ml) * 256 + kb * 32 + q * 8;
            float4 x0 = ((const float4*)s)[0], x1 = ((const float4*)s)[1];
            float va[8] = {x0.x, x0.y, x0.z, x0.w, x1.x, x1.y, x1.z, x1.w};
            af[fi].f = pack8(va);
        }
        #pragma unroll
        for (int fj = 0; fj < 8; ++fj) {
            int nl = wc + fj * 16 + l15;
            bf8[fj].f = *(const float4*)&Bs[nl * 32 + ((q ^ ((nl >> 1) & 3)) << 3)];
        }
        #pragma unroll
        for (int fi = 0; fi < 2; ++fi)
            #pragma unroll
            for (int fj = 0; fj < 8; ++fj)
                acc[fi][fj] = __builtin_amdgcn_mfma_f32_16x16x32_bf16(
                    bf8[fj].v, af[fi].v, acc[fi][fj], 0, 0, 0);
        __syncthreads();
    }

    #pragma unroll
    for (int fi = 0; fi < 2; ++fi) {
        int rg = R0 + wr + fi * 16 + l15;
        #pragma unroll
        for (int fj = 0; fj < 8; ++fj) {
            int cl = wc + fj * 16 + q * 4;
            union { u16 u[4]; float2 f; } pk;
            #pragma unroll
            for (int i = 0; i < 4; ++i) pk.u[i] = f2bf(acc[fi][fj][i]);
            *(float2*)&G[(size_t)rg * 256 + cl] = pk.f;
        }
    }
}

// ---------------------------------------------------------------- 3-NN v9
// 64 queries/block, grid 1024 (4 blocks/CU). 8 partitions x 2 queries/lane:
// thread (lq,p) scans 256 pts for queries lq and lq+32 — one ds_read feeds
// two evals. Partition merge via shfl_xor butterfly over the 8 partition
// lanes (no LDS arrays). LDS = pts only (8 x 257 float4, conflict-free).
__global__ __launch_bounds__(256) void knn_kernel(
    const float* __restrict__ xyz1, const float* __restrict__ xyz2,
    int* __restrict__ idxb, float* __restrict__ wb) {
    __shared__ float4 pts[8 * 257];       // 32.9 KB
    int t = threadIdx.x;
    int bq = blockIdx.x;                  // 0..1023
    int b = bq >> 7;                      // 128 blocks per batch
    const float* x2b = xyz2 + (size_t)b * SS_PTS * 3;
    for (int j = t; j < SS_PTS; j += 256) {
        float x = x2b[j * 3 + 0], y = x2b[j * 3 + 1], z = x2b[j * 3 + 2];
        pts[(j >> 8) * 257 + (j & 255)] = make_float4(x, y, z, x * x + y * y + z * z);
    }
    int lq = t >> 3, p = t & 7;           // lq 0..31, p 0..7
    int ga = bq * 64 + lq, gb = ga + 32;
    float qxa = xyz1[(size_t)ga * 3 + 0];
    float qya = xyz1[(size_t)ga * 3 + 1];
    float qza = xyz1[(size_t)ga * 3 + 2];
    float qxb = xyz1[(size_t)gb * 3 + 0];
    float qyb = xyz1[(size_t)gb * 3 + 1];
    float qzb = xyz1[(size_t)gb * 3 + 2];
    __syncthreads();

    float m2xa = -2.0f * qxa, m2ya = -2.0f * qya, m2za = -2.0f * qza;
    float m2xb = -2.0f * qxb, m2yb = -2.0f * qyb, m2zb = -2.0f * qzb;
    float d0a = 3.4e38f, d1a = 3.4e38f, d2a = 3.4e38f;
    float d0b = 3.4e38f, d1b = 3.4e38f, d2b = 3.4e38f;
    int j0a = 0, j1a = 0, j2a = 0, j0b = 0, j1b = 0, j2b = 0;
    int base = p * 257, sbase = p * 256;
    #pragma unroll 4
    for (int s = 0; s < 256; ++s) {
        float4 pt = pts[base + s];
        int idx = sbase + s;
        float sca = fmaf(m2xa, pt.x, fmaf(m2ya, pt.y, fmaf(m2za, pt.z, pt.w)));
        float scb = fmaf(m2xb, pt.x, fmaf(m2yb, pt.y, fmaf(m2zb, pt.z, pt.w)));
        bool a0 = sca < d0a, a1 = sca < d1a, a2 = sca < d2a;
        d2a = a1 ? d1a : (a2 ? sca : d2a); j2a = a1 ? j1a : (a2 ? idx : j2a);
        d1a = a0 ? d0a : (a1 ? sca : d1a); j1a = a0 ? j0a : (a1 ? idx : j1a);
        d0a = a0 ? sca : d0a;              j0a = a0 ? idx : j0a;
        bool b0 = scb < d0b, b1 = scb < d1b, b2 = scb < d2b;
        d2b = b1 ? d1b : (b2 ? scb : d2b); j2b = b1 ? j1b : (b2 ? idx : j2b);
        d1b = b0 ? d0b : (b1 ? scb : d1b); j1b = b0 ? j0b : (b1 ? idx : j1b);
        d0b = b0 ? scb : d0b;              j0b = b0 ? idx : j0b;
    }

    // ---- butterfly merge across the 8 partition lanes (xor 1,2,4).
    // Own entries survive ties (strict <) -> lower partition (= lower index
    // range) wins, matching the sequential scan's tie-break.
    #pragma unroll
    for (int d = 1; d < 8; d <<= 1) {
        float n0a = __shfl_xor(d0a, d, 8), n1a = __shfl_xor(d1a, d, 8), n2a = __shfl_xor(d2a, d, 8);
        int   m0a = __shfl_xor(j0a, d, 8), m1a = __shfl_xor(j1a, d, 8), m2a = __shfl_xor(j2a, d, 8);
        float n0b = __shfl_xor(d0b, d, 8), n1b = __shfl_xor(d1b, d, 8), n2b = __shfl_xor(d2b, d, 8);
        int   m0b = __shfl_xor(j0b, d, 8), m1b = __shfl_xor(j1b, d, 8), m2b = __shfl_xor(j2b, d, 8);
        bool lower = (p & d) == 0;
        float sc; int idx; bool c0, c1, c2;
        // insert neighbor's 3 (ascending) into A's list; on lower lanes use
        // strict < (own wins ties), on upper lanes use <= (neighbor = lower
        // partition wins ties) so all lanes converge to the same result.
        #define INS_A(nd, nj) \
            sc = nd; idx = nj; \
            c0 = lower ? (sc < d0a) : (sc <= d0a); \
            c1 = lower ? (sc < d1a) : (sc <= d1a); \
            c2 = lower ? (sc < d2a) : (sc <= d2a); \
            d2a = c1 ? d1a : (c2 ? sc : d2a); j2a = c1 ? j1a : (c2 ? idx : j2a); \
            d1a = c0 ? d0a : (c1 ? sc : d1a); j1a = c0 ? j0a : (c1 ? idx : j1a); \
            d0a = c0 ? sc : d0a;              j0a = c0 ? idx : j0a;
        #define INS_B(nd, nj) \
            sc = nd; idx = nj; \
            c0 = lower ? (sc < d0b) : (sc <= d0b); \
            c1 = lower ? (sc < d1b) : (sc <= d1b); \
            c2 = lower ? (sc < d2b) : (sc <= d2b); \
            d2b = c1 ? d1b : (c2 ? sc : d2b); j2b = c1 ? j1b : (c2 ? idx : j2b); \
            d1b = c0 ? d0b : (c1 ? sc : d1b); j1b = c0 ? j0b : (c1 ? idx : j1b); \
            d0b = c0 ? sc : d0b;              j0b = c0 ? idx : j0b;
        INS_A(n0a, m0a) INS_A(n1a, m1a) INS_A(n2a, m2a)
        INS_B(n0b, m0b) INS_B(n1b, m1b) INS_B(n2b, m2b)
        #undef INS_A
        #undef INS_B
    }

    if (p == 0) {
        float qqa = qxa * qxa + qya * qya + qza * qza;
        float dd0 = fmaxf(d0a + qqa, 1e-10f);
        float dd1 = fmaxf(d1a + qqa, 1e-10f);
        float dd2 = fmaxf(d2a + qqa, 1e-10f);
        float w0 = 1.0f / dd0, w1 = 1.0f / dd1, w2 = 1.0f / dd2;
        float inv = 1.0f / (w0 + w1 + w2);
        idxb[(size_t)ga * 3 + 0] = j0a;
        idxb[(size_t)ga * 3 + 1] = j1a;
        idxb[(size_t)ga * 3 + 2] = j2a;
        wb[(size_t)ga * 3 + 0] = w0 * inv;
        wb[(size_t)ga * 3 + 1] = w1 * inv;
        wb[(size_t)ga * 3 + 2] = w2 * inv;
        float qqb = qxb * qxb + qyb * qyb + qzb * qzb;
        float e0 = fmaxf(d0b + qqb, 1e-10f);
        float e1 = fmaxf(d1b + qqb, 1e-10f);
        float e2 = fmaxf(d2b + qqb, 1e-10f);
        float v0 = 1.0f / e0, v1 = 1.0f / e1, v2 = 1.0f / e2;
        float vin = 1.0f / (v0 + v1 + v2);
        idxb[(size_t)gb * 3 + 0] = j0b;
        idxb[(size_t)gb * 3 + 1] = j1b;
        idxb[(size_t)gb * 3 + 2] = j2b;
        wb[(size_t)gb * 3 + 0] = v0 * vin;
        wb[(size_t)gb * 3 + 1] = v1 * vin;
        wb[(size_t)gb * 3 + 2] = v2 * vin;
    }
}

// ---------------------------------------------------------------- GEMM1 (R7)
// h1 = points1 @ W1a^T (K=64 MFMA) + Sum_k w_k * G[idx_k].
// Stats via shfl-reduce into per-wave-pair LDS slices (no atomics).
__global__ __launch_bounds__(256, 3) void gemm1_kernel(
    const float* __restrict__ points1, const u16* __restrict__ G,
    const int* __restrict__ idxb, const float* __restrict__ wb,
    const u16* __restrict__ wt1b, u16* __restrict__ h1, float* __restrict__ part1) {
    __shared__ __align__(16) u16 Si[64 * 258];     // interp bf16, stride 258
    __shared__ __align__(16) u16 Bs[8192];         // W1a tile 256x32, swizzled
    __shared__ float bsum[2][256], bsq[2][256];    // per-wave-pair slices

    int t = threadIdx.x, bx = blockIdx.x;
    int batch = bx & 7;
    int R0 = batch * 8192 + (bx >> 3) * 64;
    const u16* Gb = G + (size_t)batch * SS_PTS * 256;

    int w = t >> 6, l = t & 63, l15 = l & 15, q = l >> 4;
    int wr = (w >> 1) * 32, wc = (w & 1) * 128;

    // ---- phase 1: gather-sum from G into Si; one wave per query row
    {
        #pragma unroll 4
        for (int e = 0; e < 16; ++e) {
            int qi = w * 16 + e;
            size_t gq = (size_t)(R0 + qi) * 3;
            int i0 = idxb[gq + 0], i1 = idxb[gq + 1], i2 = idxb[gq + 2];
            float w0 = wb[gq + 0], w1 = wb[gq + 1], w2 = wb[gq + 2];
            union { float2 f; u16 u[4]; } g0, g1, g2;
            g0.f = *(const float2*)(Gb + (size_t)i0 * 256 + l * 4);
            g1.f = *(const float2*)(Gb + (size_t)i1 * 256 + l * 4);
            g2.f = *(const float2*)(Gb + (size_t)i2 * 256 + l * 4);
            union { u16 u[4]; float2 f; } pk;
            #pragma unroll
            for (int i = 0; i < 4; ++i) {
                float v = fmaf(w0, bf2f(g0.u[i]),
                          fmaf(w1, bf2f(g1.u[i]), w2 * bf2f(g2.u[i])));
                pk.u[i] = f2bf(v);
            }
            *(float2*)&Si[qi * 258 + l * 4] = pk.f;
        }
    }

    // ---- B staging regs (W1a rows, k 0..63)
    int bm = t >> 1, bh = t & 1;
    int sb0 = (bm >> 1) & 3, sb1 = ((bm + 128) >> 1) & 3;
    const u16* wsrc0 = wt1b + (size_t)bm * 320 + bh * 16;
    const u16* wsrc1 = wt1b + (size_t)(bm + 128) * 320 + bh * 16;
    float4 pb0 = ((const float4*)wsrc0)[0], pb1 = ((const float4*)wsrc0)[1];
    float4 pb2 = ((const float4*)wsrc1)[0], pb3 = ((const float4*)wsrc1)[1];

    f32x4 acc[2][8];
    #pragma unroll
    for (int i = 0; i < 2; ++i)
        #pragma unroll
        for (int j = 0; j < 8; ++j) acc[i][j] = (f32x4){0.f, 0.f, 0.f, 0.f};

    // ---- phase 2: K-loop (2 x K=32) on points1 @ W1a^T
    #pragma unroll
    for (int kb = 0; kb < 2; ++kb) {
        *(float4*)&Bs[bm * 32 + (((bh * 2 + 0) ^ sb0) << 3)] = pb0;
        *(float4*)&Bs[bm * 32 + (((bh * 2 + 1) ^ sb0) << 3)] = pb1;
        *(float4*)&Bs[(bm + 128) * 32 + (((bh * 2 + 0) ^ sb1) << 3)] = pb2;
        *(float4*)&Bs[(bm + 128) * 32 + (((bh * 2 + 1) ^ sb1) << 3)] = pb3;
        __syncthreads();
        if (kb == 0) {
            pb0 = ((const float4*)(wsrc0 + 32))[0];
            pb1 = ((const float4*)(wsrc0 + 32))[1];
            pb2 = ((const float4*)(wsrc1 + 32))[0];
            pb3 = ((const float4*)(wsrc1 + 32))[1];
        }
        union uf { float4 f; bf16x8 v; };
        uf af[2], bf8[8];
        #pragma unroll
        for (int fi = 0; fi < 2; ++fi) {
            int ml = wr + fi * 16 + l15;
            const float* s = points1 + (size_t)(R0 + ml) * 64 + kb * 32 + q * 8;
            float4 x0 = ((const float4*)s)[0], x1 = ((const float4*)s)[1];
            float va[8] = {x0.x, x0.y, x0.z, x0.w, x1.x, x1.y, x1.z, x1.w};
            af[fi].f = pack8(va);
        }
        #pragma unroll
        for (int fj = 0; fj < 8; ++fj) {
            int nl = wc + fj * 16 + l15;
            bf8[fj].f = *(const float4*)&Bs[nl * 32 + ((q ^ ((nl >> 1) & 3)) << 3)];
        }
        #pragma unroll
        for (int fi = 0; fi < 2; ++fi)
            #pragma unroll
            for (int fj = 0; fj < 8; ++fj)
                acc[fi][fj] = __builtin_amdgcn_mfma_f32_16x16x32_bf16(
                    bf8[fj].v, af[fi].v, acc[fi][fj], 0, 0, 0);
        __syncthreads();
    }

    // ---- epilogue: add interp (Si), store h1 K-tiled, stats via shfl (no atomics)
    #pragma unroll
    for (int fj = 0; fj < 8; ++fj) {
        int c0 = wc + fj * 16 + q * 4;
        float s[4], sq[4];
        #pragma unroll
        for (int i = 0; i < 4; ++i) { s[i] = 0.0f; sq[i] = 0.0f; }
        #pragma unroll
        for (int fi = 0; fi < 2; ++fi) {
            int rl = wr + fi * 16 + l15;
            int rg = R0 + rl;
            union { float2 f; u16 u[4]; } si;
            si.f = *(const float2*)&Si[rl * 258 + c0];
            union { u16 u[4]; float2 f; } pk;
            #pragma unroll
            for (int i = 0; i < 4; ++i) {
                float v = acc[fi][fj][i] + bf2f(si.u[i]);
                pk.u[i] = f2bf(v);
                s[i] += v; sq[i] += v * v;
            }
            *(float2*)&h1[((size_t)(c0 >> 5) * 65536 + rg) * 32 + (c0 & 31)] = pk.f;
        }
        #pragma unroll
        for (int i = 0; i < 4; ++i) {
            #pragma unroll
            for (int d = 1; d < 16; d <<= 1) {
                s[i]  += __shfl_xor(s[i], d, 16);
                sq[i] += __shfl_xor(sq[i], d, 16);
            }
        }
        if (l15 == 0) {
            int half = w >> 1;
            #pragma unroll
            for (int i = 0; i < 4; ++i) {
                bsum[half][c0 + i] = s[i];
                bsq[half][c0 + i]  = sq[i];
            }
        }
    }
    __syncthreads();
    part1[(size_t)bx * 512 + t * 2 + 0] = bsum[0][t] + bsum[1][t];
    part1[(size_t)bx * 512 + t * 2 + 1] = bsq[0][t] + bsq[1][t];
}

// ---------------------------------------------------------------- stats reduce
__global__ __launch_bounds__(256) void reduce_kernel(
    const float* __restrict__ part, int nblk, int C, float invM,
    const float* __restrict__ gam, const float* __restrict__ bet,
    float* __restrict__ st) {
    __shared__ float red[256];
    int t = threadIdx.x;
    int slot = t & 31, ig = t >> 5;
    int cb = blockIdx.x * 16;
    float p = 0.0f;
    for (int i = ig; i < nblk; i += 8)
        p += part[(size_t)i * (2 * C) + cb * 2 + slot];
    red[t] = p;
    __syncthreads();
    if (t < 32) {
        float tot = red[t];
        #pragma unroll
        for (int k = 1; k < 8; ++k) tot += red[k * 32 + t];
        red[t] = tot;
    }
    __syncthreads();
    if (t < 16) {
        int c = cb + t;
        float sum = red[2 * t], sq = red[2 * t + 1];
        float mean = sum * invM;
        float var  = sq * invM - mean * mean;
        float rs   = rsqrtf(var + 1e-5f);
        float scv  = gam[c] * rs;
        st[c]     = scv;
        st[C + c] = bet[c] - mean * scv;
    }
}

// ---------------------------------------------------------------- GEMM2 (R7)
// 64x128 tile, grid 1024, LDS dbuf + reg prefetch. Stats: shfl + per-wave
// LDS slices (no atomics).
__global__ __launch_bounds__(256, 4) void gemm2_kernel(
    const u16* __restrict__ h1, const u16* __restrict__ wt2b,
    const float* __restrict__ st1,
    u16* __restrict__ h2, float* __restrict__ part2) {
    __shared__ __align__(16) u16 As[2][64 * 32];
    __shared__ __align__(16) u16 Bs[2][128 * 32];
    __shared__ float sc1[256], sh1[256];
    __shared__ float bsum2[4][128], bsq2[4][128];

    int t = threadIdx.x;
    int bx = blockIdx.x;
    int R0 = bx * 64;
    sc1[t] = st1[t];
    sh1[t] = st1[256 + t];

    int w = t >> 6, l = t & 63, l15 = l & 15, q = l >> 4;
    int wr = w * 16;
    int arow = t >> 2, ac8 = (t & 3) << 3, sa = (arow >> 1) & 3;
    int bm = t >> 1, bh = t & 1, sb = (bm >> 1) & 3;

    union lda_t { float4 f; u16 u[8]; };
    lda_t pa; float4 pb0, pb1;
    const u16* bsrc = wt2b + (size_t)bm * 256 + bh * 16;

    pa.f = *(const float4*)(h1 + ((size_t)0 * 65536 + R0 + arow) * 32 + ac8);
    pb0 = ((const float4*)bsrc)[0];
    pb1 = ((const float4*)bsrc)[1];

    f32x4 acc[8];
    #pragma unroll
    for (int j = 0; j < 8; ++j) acc[j] = (f32x4){0.f, 0.f, 0.f, 0.f};

    __syncthreads();   // sc1/sh1 visible

    {
        float o[8];
        #pragma unroll
        for (int j = 0; j < 8; ++j)
            o[j] = fmaxf(fmaf(bf2f(pa.u[j]), sc1[ac8 + j], sh1[ac8 + j]), 0.0f);
        *(float4*)&As[0][arow * 32 + (((ac8 >> 3) ^ sa) << 3)] = pack8(o);
        *(float4*)&Bs[0][bm * 32 + (((bh * 2 + 0) ^ sb) << 3)] = pb0;
        *(float4*)&Bs[0][bm * 32 + (((bh * 2 + 1) ^ sb) << 3)] = pb1;
    }
    __syncthreads();

    #pragma unroll
    for (int kb = 0; kb < 8; ++kb) {
        if (kb < 7) {
            pa.f = *(const float4*)(h1 + ((size_t)(kb + 1) * 65536 + R0 + arow) * 32 + ac8);
            pb0 = ((const float4*)(bsrc + (kb + 1) * 32))[0];
            pb1 = ((const float4*)(bsrc + (kb + 1) * 32))[1];
        }
        int buf = kb & 1;
        union uf { float4 f; bf16x8 v; };
        uf af, bf8[8];
        {
            int ml = wr + l15;
            af.f = *(const float4*)&As[buf][ml * 32 + ((q ^ ((ml >> 1) & 3)) << 3)];
        }
        #pragma unroll
        for (int fj = 0; fj < 8; ++fj) {
            int nl = fj * 16 + l15;
            bf8[fj].f = *(const float4*)&Bs[buf][nl * 32 + ((q ^ ((nl >> 1) & 3)) << 3)];
        }
        #pragma unroll
        for (int fj = 0; fj < 8; ++fj)
            acc[fj] = __builtin_amdgcn_mfma_f32_16x16x32_bf16(
                bf8[fj].v, af.v, acc[fj], 0, 0, 0);
        if (kb < 7) {
            int ch0 = (kb + 1) * 32 + ac8;
            float o[8];
            #pragma unroll
            for (int j = 0; j < 8; ++j)
                o[j] = fmaxf(fmaf(bf2f(pa.u[j]), sc1[ch0 + j], sh1[ch0 + j]), 0.0f);
            *(float4*)&As[buf ^ 1][arow * 32 + (((ac8 >> 3) ^ sa) << 3)] = pack8(o);
            *(float4*)&Bs[buf ^ 1][bm * 32 + (((bh * 2 + 0) ^ sb) << 3)] = pb0;
            *(float4*)&Bs[buf ^ 1][bm * 32 + (((bh * 2 + 1) ^ sb) << 3)] = pb1;
        }
        __syncthreads();
    }

    // ---- epilogue: h2 store + stats via shfl into per-wave slices (no atomics)
    int rg = R0 + wr + l15;
    #pragma unroll
    for (int fj = 0; fj < 8; ++fj) {
        int cl = fj * 16 + q * 4;
        union { u16 u[4]; float2 f; } pk;
        float s[4], sq[4];
        #pragma unroll
        for (int i = 0; i < 4; ++i) {
            float v = acc[fj][i];
            pk.u[i] = f2bf(v);
            s[i] = v; sq[i] = v * v;
        }
        *(float2*)&h2[(size_t)rg * 128 + cl] = pk.f;
        #pragma unroll
        for (int i = 0; i < 4; ++i) {
            #pragma unroll
            for (int d = 1; d < 16; d <<= 1) {
                s[i]  += __shfl_xor(s[i], d, 16);
                sq[i] += __shfl_xor(sq[i], d, 16);
            }
        }
        if (l15 == 0) {
            #pragma unroll
            for (int i = 0; i < 4; ++i) {
                bsum2[w][cl + i] = s[i];
                bsq2[w][cl + i]  = sq[i];
            }
        }
    }
    __syncthreads();
    if (t < 128) {
        part2[(size_t)bx * 256 + t * 2 + 0] =
            bsum2[0][t] + bsum2[1][t] + bsum2[2][t] + bsum2[3][t];
        part2[(size_t)bx * 256 + t * 2 + 1] =
            bsq2[0][t] + bsq2[1][t] + bsq2[2][t] + bsq2[3][t];
    }
}

// ---------------------------------------------------------------- final BN2 + relu
__global__ __launch_bounds__(256) void final_kernel(
    const u16* __restrict__ h2, const float* __restrict__ st2,
    float* __restrict__ out) {
    __shared__ float lst[256];
    int t = threadIdx.x;
    lst[t] = st2[t];
    __syncthreads();
    size_t e0 = ((size_t)blockIdx.x * 256 + t) * 8;
    int c0 = (int)(e0 & 127);
    union { float4 f; u16 u[8]; } ld;
    ld.f = *(const float4*)(h2 + e0);
    float o[8];
    #pragma unroll
    for (int j = 0; j < 8; ++j) {
        int c = c0 + j;
        float v = fmaf(bf2f(ld.u[j]), lst[c], lst[128 + c]);
        o[j] = fmaxf(v, 0.0f);
    }
    float4* op = (float4*)(out + e0);
    float4 r0; r0.x = o[0]; r0.y = o[1]; r0.z = o[2]; r0.w = o[3];
    float4 r1; r1.x = o[4]; r1.y = o[5]; r1.z = o[6]; r1.w = o[7];
    op[0] = r0;
    op[1] = r1;
}

// ----------------------------------------------------------------
extern "C" void kernel_launch(void* const* d_in, const int* in_sizes, int n_in,
                              void* d_out, int out_size, void* d_ws, size_t ws_size,
                              hipStream_t stream) {
    (void)in_sizes; (void)n_in; (void)out_size; (void)ws_size;
    const float* xyz1    = (const float*)d_in[0];
    const float* xyz2    = (const float*)d_in[1];
    const float* points1 = (const float*)d_in[2];
    const float* points2 = (const float*)d_in[3];
    const float* W1      = (const float*)d_in[4];
    const float* g1      = (const float*)d_in[5];
    const float* b1      = (const float*)d_in[6];
    const float* W2      = (const float*)d_in[7];
    const float* g2      = (const float*)d_in[8];
    const float* b2      = (const float*)d_in[9];

    char* ws = (char*)d_ws;
    int*   idxb = (int*)(ws + OFF_IDX);
    float* wb   = (float*)(ws + OFF_W);
    u16*   wt1b = (u16*)(ws + OFF_WT1B);
    u16*   wt2b = (u16*)(ws + OFF_WT2B);
    float* st1  = (float*)(ws + OFF_ST1);
    float* st2  = (float*)(ws + OFF_ST2);
    float* p1   = (float*)(ws + OFF_P1);
    float* p2   = (float*)(ws + OFF_P2);
    u16*   h1   = (u16*)(ws + OFF_H1);
    u16*   h2   = (u16*)(ws + OFF_H2);
    u16*   G    = (u16*)(ws + OFF_H2);   // reuse: consumed before h2 is written
    float* outp = (float*)d_out;

    prep_kernel<<<320, 256, 0, stream>>>(W1, W2, wt1b, wt2b);
    gemm0_kernel<<<256, 256, 0, stream>>>(points2, wt1b, G);
    knn_kernel<<<1024, 256, 0, stream>>>(xyz1, xyz2, idxb, wb);
    gemm1_kernel<<<1024, 256, 0, stream>>>(points1, G, idxb, wb, wt1b, h1, p1);
    reduce_kernel<<<16, 256, 0, stream>>>(p1, 1024, 256, 1.0f / 65536.0f, g1, b1, st1);
    gemm2_kernel<<<1024, 256, 0, stream>>>(h1, wt2b, st1, h2, p2);
    reduce_kernel<<<8, 256, 0, stream>>>(p2, 1024, 128, 1.0f / 65536.0f, g2, b2, st2);
    final_kernel<<<4096, 256, 0, stream>>>(h2, st2, outp);
}